// Round 18
// baseline (181.255 us; speedup 1.0000x reference)
//
#include <hip/hip_runtime.h>

#define PPX  128
#define PP2  16384
#define IMH  896
#define IMW  896
#define NB   24
#define NI   8
#define HP   1152
#define WP   1152
#define MAXG 6              // scheduled levels 0..5; lvl>=6 -> fallback (rare)
#define NMB  (NI*NB)        // 192 boxes; *8 chunks = 1536 mask blocks
#define NCPY 2048
#define NCR0 (NI*NB*32)     // 6144 crop0 blocks (per-box assignment)
#define M1   12

// ws layout (float units):
// [0..5]                      mu_p[3], sd_p[3]
// [8 .. 8+192*8)              per-box structs
// [2048 .. +192*512)          mask bitmaps (uint32)
// [100352 .. +8*32)           schedule: per image lvl[24] + cnt[MAXG] at [24..] (uint32)
// [100608 .. +8*6*24)         member lists [img][lvl][24] (uint32)
// [101760 .. +192*8)          mask-sum partials [box][chunk]
// [103424 .. +8*24*32*6)      partial stats [box][blk][6]
// [140288 .. +8*24*PP2*3)     pbg slot per box (~38 MB)
#define WS_BOX  8
#define WS_MASK 2048
#define WS_SCH  100352
#define WS_LIST 100608
#define WS_MSUM 101760
#define WS_PART 103424
#define WS_PBG  140288

__device__ __forceinline__ void box_geom(const float* __restrict__ bx,
    const float* __restrict__ Wsc, const float* __restrict__ bsc,
    float& scale, float& ps, int& yi, int& xi, int& ph, int& vld)
{
  float ya=bx[0], xa=bx[1], yb=bx[2], xb=bx[3];
  float bh=(yb-ya)/(float)IMH, bw=(xb-xa)/(float)IMW;
  float z = bh*Wsc[0]+bw*Wsc[1]+bsc[0];
  float sig = 1.f/(1.f+expf(-z));
  scale = sig*0.4f;
  float h=yb-ya, w=xb-xa;
  ps = floorf(sqrtf((h*w)*scale));
  float oy=ya+h*0.5f, ox=xa+w*0.5f;
  float ymp=fmaxf(oy-ps*0.5f,0.f), xmp=fmaxf(ox-ps*0.5f,0.f);
  if (ymp+ps>(float)IMH) ymp=(float)IMH-ps;
  if (xmp+ps>(float)IMW) xmp=(float)IMW-ps;
  yi=(int)ymp; xi=(int)xmp; ph=(int)ps;
  vld = (ps>60.f) ? 1 : 0;
}

// paste value at region-relative (rr,cc); expressions verbatim from passing rounds.
__device__ __forceinline__ void analytic3(int rr, int cc, float phf,
    const float* __restrict__ pbg1, const float* __restrict__ patch,
    const unsigned* msk, const float* ab, float v[3])
{
  float sy = ((rr + 0.5f)*128.0f)/phf - 0.5f;
  float sx = ((cc + 0.5f)*128.0f)/phf - 0.5f;
  sy = fminf(fmaxf(sy, 0.f), 127.f);
  sx = fminf(fmaxf(sx, 0.f), 127.f);
  float fy0 = floorf(sy), fx0 = floorf(sx);
  int py0 = (int)fy0, px0 = (int)fx0;
  int py1 = py0 + 1 < 127 ? py0 + 1 : 127;
  int px1 = px0 + 1 < 127 ? px0 + 1 : 127;
  float wy = sy - fy0, wx = sx - fx0;
  int i00 = (py0<<7)+px0, i01 = (py0<<7)+px1, i10 = (py1<<7)+px0, i11 = (py1<<7)+px1;
  bool m00 = (msk[i00>>5] >> (i00&31)) & 1u;
  bool m01 = (msk[i01>>5] >> (i01&31)) & 1u;
  bool m10 = (msk[i10>>5] >> (i10&31)) & 1u;
  bool m11 = (msk[i11>>5] >> (i11&31)) & 1u;
  #pragma unroll
  for (int ch = 0; ch < 3; ++ch) {
    float a = ab[ch], be = ab[3+ch];
    float t00 = m00 ? patch[i00*3+ch]*a + be : pbg1[i00*3+ch];
    float t01 = m01 ? patch[i01*3+ch]*a + be : pbg1[i01*3+ch];
    float t10 = m10 ? patch[i10*3+ch]*a + be : pbg1[i10*3+ch];
    float t11 = m11 ? patch[i11*3+ch]*a + be : pbg1[i11*3+ch];
    v[ch] = (1.f-wy)*((1.f-wx)*t00 + wx*t01) + wy*((1.f-wx)*t10 + wx*t11);
  }
}

// plain crop with explicit geom: box n of image b, block blk (512 px), from src.
__device__ __forceinline__ void crop_geom(
    const float* __restrict__ src, float* __restrict__ ws, int b, int n,
    int yi, int xi, int ph, int blk, float (*s_red)[6])
{
  const int tid = threadIdx.x;
  const float phf = (float)(ph > 1 ? ph : 1);
  float* __restrict__ pbg = ws + WS_PBG + (size_t)(b*NB + n)*PP2*3;
  float sm[3] = {0,0,0}, sq[3] = {0,0,0};
  #pragma unroll
  for (int k = 0; k < 2; ++k) {
    int idx = blk*512 + k*256 + tid;
    int py = idx >> 7, px = idx & 127;
    float ys = ((float)yi + (py + 0.5f)*phf*(1.0f/PPX)) - 0.5f;
    float xs = ((float)xi + (px + 0.5f)*phf*(1.0f/PPX)) - 0.5f;
    ys = fminf(fmaxf(ys, 0.f), (float)(HP-1));
    xs = fminf(fmaxf(xs, 0.f), (float)(WP-1));
    float fy0 = floorf(ys), fx0 = floorf(xs);
    int y0 = (int)fy0, x0 = (int)fx0;
    int y1 = y0 + 1 < HP-1 ? y0 + 1 : HP-1;
    int x1 = x0 + 1 < WP-1 ? x0 + 1 : WP-1;
    float wy = ys - fy0, wx = xs - fx0;
    bool y0i = y0 < IMH, y1i = y1 < IMH, x0i = x0 < IMW, x1i = x1 < IMW;
    const float* r0 = src + (size_t)y0*IMW*3;
    const float* r1 = src + (size_t)y1*IMW*3;
    #pragma unroll
    for (int c = 0; c < 3; ++c) {
      float v00 = (y0i && x0i) ? r0[x0*3+c] : 0.f;
      float v01 = (y0i && x1i) ? r0[x1*3+c] : 0.f;
      float v10 = (y1i && x0i) ? r1[x0*3+c] : 0.f;
      float v11 = (y1i && x1i) ? r1[x1*3+c] : 0.f;
      float v = (1.f-wy)*((1.f-wx)*v00 + wx*v01) + wy*((1.f-wx)*v10 + wx*v11);
      pbg[idx*3+c] = v;
      sm[c] += v; sq[c] += v*v;
    }
  }
  float vals[6] = {sm[0],sm[1],sm[2],sq[0],sq[1],sq[2]};
  #pragma unroll
  for (int off = 32; off; off >>= 1)
    #pragma unroll
    for (int k = 0; k < 6; ++k) vals[k] += __shfl_down(vals[k], off);
  int wid = tid >> 6;
  __syncthreads();
  if ((tid & 63) == 0)
    for (int k = 0; k < 6; ++k) s_red[wid][k] = vals[k];
  __syncthreads();
  if (tid == 0) {
    float* part = ws + WS_PART + (size_t)((b*NB + n)*32 + blk)*6;
    for (int k = 0; k < 6; ++k)
      part[k] = s_red[0][k] + s_red[1][k] + s_red[2][k] + s_red[3][k];
  }
}

// --- first_k: [copy 2048 | masks 1536 | crop0-by-box 6144 | stats | sched] ---
__global__ __launch_bounds__(256) void first_k(
    float* __restrict__ out, const float* __restrict__ images,
    const float* __restrict__ boxes,
    const float* __restrict__ Wsc, const float* __restrict__ bsc,
    const float* __restrict__ Wg, const float* __restrict__ bgv,
    const float* __restrict__ patch, float* __restrict__ ws)
{
  const int bid = blockIdx.x, tid = threadIdx.x;

  if (bid < NCPY) {
    // ---- dedicated copy blocks at the FRONT: start at t=0, full width ----
    const float4* src4 = (const float4*)images;
    float4* dst4 = (float4*)out;
    const int n4 = NI*IMH*IMW*3/4;
    for (int i = bid*256 + tid; i < n4; i += NCPY*256) dst4[i] = src4[i];
    return;
  }

  if (bid < NCPY + NMB*8) {
    // ---- mask chunk q of box bn ----
    const int w = bid - NCPY;
    const int bn = w >> 3, q = w & 7;
    float bh = (boxes[bn*4+2]-boxes[bn*4+0])/(float)IMH;
    float bw = (boxes[bn*4+3]-boxes[bn*4+1])/(float)IMW;
    unsigned* mwords = ((unsigned*)ws) + WS_MASK + bn*512;
    float lsum = 0.f;
    const int lane = tid & 63;
    #pragma unroll
    for (int i = 0; i < 8; ++i) {
      int p = q*2048 + i*256 + tid;
      float zz = bh*Wg[p] + bw*Wg[PP2 + p] + bgv[p];
      lsum += 1.0f / (1.0f + expf(-zz));
      unsigned long long m = __ballot(zz > 0.0f);
      if (lane == 0) {
        int base = p >> 5;
        mwords[base]   = (unsigned)(m & 0xffffffffULL);
        mwords[base+1] = (unsigned)(m >> 32);
      }
    }
    #pragma unroll
    for (int off = 32; off; off >>= 1) lsum += __shfl_down(lsum, off);
    __shared__ float s_r[4];
    if ((tid & 63) == 0) s_r[tid >> 6] = lsum;
    __syncthreads();
    if (tid == 0) ws[WS_MSUM + bn*8 + q] = s_r[0] + s_r[1] + s_r[2] + s_r[3];
    return;
  }

  if (bid < NCPY + NMB*8 + NCR0) {
    // ---- crop0 block: box n of image b, block blk; self-determined membership ----
    const int w = bid - NCPY - NMB*8;
    const int b = w / (NB*32);
    const int rem = w - b*(NB*32);
    const int n = rem >> 5, blk = rem & 31;
    __shared__ int s_yi[NB], s_xi[NB], s_ph[NB], s_vl[NB];
    __shared__ int s_ok;
    __shared__ float s_red[4][6];
    if (tid < NB) {
      float scale, ps; int yi, xi, ph, vld;
      box_geom(boxes + (b*NB + tid)*4, Wsc, bsc, scale, ps, yi, xi, ph, vld);
      s_yi[tid]=yi; s_xi[tid]=xi; s_ph[tid]=ph; s_vl[tid]=vld;
    }
    __syncthreads();
    if (tid == 0) {
      int ok = s_vl[n];
      if (ok) {
        int y0=s_yi[n]-2, y1=s_yi[n]+s_ph[n]+3;
        int x0=s_xi[n]-2, x1=s_xi[n]+s_ph[n]+3;
        for (int m = 0; m < n; ++m) {
          if (!s_vl[m]) continue;
          int my0=s_yi[m]-2, my1=s_yi[m]+s_ph[m]+3;
          int mx0=s_xi[m]-2, mx1=s_xi[m]+s_ph[m]+3;
          if (y0<my1 && my0<y1 && x0<mx1 && mx0<x1) { ok = 0; break; }
        }
      }
      s_ok = ok;
    }
    __syncthreads();
    if (!s_ok) return;
    crop_geom(images + (size_t)b*IMH*IMW*3, ws, b, n, s_yi[n], s_xi[n], s_ph[n], blk, s_red);
    return;
  }

  if (bid == NCPY + NMB*8 + NCR0) {
    // ---- patch stats ----
    __shared__ float s_red6[256][6];
    float s0=0,s1=0,s2=0,q0=0,q1=0,q2=0;
    for (int i = tid; i < PP2; i += 256) {
      float a = patch[i*3+0], b = patch[i*3+1], c = patch[i*3+2];
      s0+=a; s1+=b; s2+=c; q0+=a*a; q1+=b*b; q2+=c*c;
    }
    s_red6[tid][0]=s0; s_red6[tid][1]=s1; s_red6[tid][2]=s2;
    s_red6[tid][3]=q0; s_red6[tid][4]=q1; s_red6[tid][5]=q2;
    __syncthreads();
    for (int s = 128; s > 0; s >>= 1) {
      if (tid < s)
        for (int k=0;k<6;++k) s_red6[tid][k] += s_red6[tid+s][k];
      __syncthreads();
    }
    if (tid == 0) {
      for (int c=0;c<3;++c) {
        float mu  = s_red6[0][c]   * (1.0f/PP2);
        float var = s_red6[0][3+c] * (1.0f/PP2) - mu*mu;
        float sd  = sqrtf(fmaxf(var, 0.f)) + 1e-6f;
        ws[c] = mu; ws[3+c] = sd;
      }
    }
    return;
  }

  // ---- last block: structs + per-image level schedule + member lists ----
  {
    __shared__ int g_yi[NI*NB], g_xi[NI*NB], g_ph[NI*NB], g_vl[NI*NB];
    if (tid < NI*NB) {
      float scale, ps; int yi, xi, ph, vld;
      box_geom(boxes + tid*4, Wsc, bsc, scale, ps, yi, xi, ph, vld);
      g_yi[tid]=yi; g_xi[tid]=xi; g_ph[tid]=ph; g_vl[tid]=vld;
      float* bst = ws + WS_BOX + tid*8;
      bst[0] = scale;
      bst[1] = ps;
      ((int*)bst)[2] = yi;
      ((int*)bst)[3] = xi;
      ((int*)bst)[4] = ph;
      bst[5] = vld ? 1.f : 0.f;
    }
    __syncthreads();
    if (tid < NI) {
      unsigned* sch = ((unsigned*)ws) + WS_SCH + tid*32;
      unsigned* lst = ((unsigned*)ws) + WS_LIST + tid*(MAXG*NB);
      int lv[NB];
      int cnt[MAXG];
      for (int L = 0; L < MAXG; ++L) cnt[L] = 0;
      for (int n = 0; n < NB; ++n) {
        int idx = tid*NB + n;
        if (!g_vl[idx]) { lv[n] = -1; sch[n] = 255u; continue; }
        int y0 = g_yi[idx]-2, y1 = g_yi[idx]+g_ph[idx]+3;
        int x0 = g_xi[idx]-2, x1 = g_xi[idx]+g_ph[idx]+3;
        int L = 0;
        for (int m = 0; m < n; ++m) {
          if (lv[m] < 0) continue;
          int mi = tid*NB + m;
          int my0 = g_yi[mi]-2, my1 = g_yi[mi]+g_ph[mi]+3;
          int mx0 = g_xi[mi]-2, mx1 = g_xi[mi]+g_ph[mi]+3;
          if (y0 < my1 && my0 < y1 && x0 < mx1 && mx0 < x1)
            L = max(L, lv[m] + 1);
        }
        lv[n] = L;
        sch[n] = (unsigned)L;
        if (L < MAXG) lst[L*NB + cnt[L]++] = (unsigned)n;
      }
      for (int L = 0; L < MAXG; ++L) sch[24 + L] = (unsigned)cnt[L];
    }
  }
}

// ------ crop_k: crop level L (>=1) from out ------
__global__ __launch_bounds__(256) void crop_k(
    float* __restrict__ out, float* __restrict__ ws, int L, int M)
{
  const int bid = blockIdx.x, tid = threadIdx.x;
  const int b = bid / (M*32);
  const int rem = bid - b*(M*32);
  const int j = rem >> 5, blk = rem & 31;
  __shared__ float s_red[4][6];
  __shared__ int s_cn[NB];
  __shared__ int s_cc;
  const unsigned* sch = ((const unsigned*)ws) + WS_SCH + b*32;
  if (tid == 0) s_cc = (int)sch[24 + L];
  __syncthreads();
  const int cc = s_cc;
  if (j >= cc) return;
  if (tid < cc) s_cn[tid] = (int)(((const unsigned*)ws) + WS_LIST + b*(MAXG*NB))[L*NB + tid];
  __syncthreads();
  const float* src = out + (size_t)b*IMH*IMW*3;
  for (int jj = j; jj < cc; jj += M) {
    const int n = s_cn[jj];
    const int* bi = (const int*)(ws + WS_BOX + (b*NB + n)*8);
    crop_geom(src, ws, b, n, bi[2], bi[3], bi[4], blk, s_red);
  }
}

// ------ paste_k: paste level L; P0 grid has +1 loss block ------
__global__ __launch_bounds__(256) void paste_k(
    float* __restrict__ out, const float* __restrict__ patch,
    float* __restrict__ ws, int L, int M)
{
  const int bid = blockIdx.x, tid = threadIdx.x;
  if (bid >= NI*M*32) {
    // loss block (only in P0's grid)
    __shared__ float l_sc[NI*NB], l_ms[NI*NB], l_vl[NI*NB];
    if (tid < NI*NB) {
      const float* bst = ws + WS_BOX + tid*8;
      l_sc[tid] = bst[0]; l_vl[tid] = bst[5];
      float ms = 0.f;
      for (int q = 0; q < 8; ++q) ms += ws[WS_MSUM + tid*8 + q];
      l_ms[tid] = ms;
    }
    __syncthreads();
    if (tid == 0) {
      float total = 0.f;
      for (int b = 0; b < NI; ++b) {
        float sum_s = 0.f, cnt = 0.f, bgl = 0.f;
        for (int n = 0; n < NB; ++n) {
          int idx = b*NB + n;
          float v = l_vl[idx];
          sum_s += l_sc[idx]*v; cnt += v; bgl += (l_ms[idx]*(1.0f/PP2))*v;
        }
        float nn = fmaxf(cnt, 1.0f);
        float m = sum_s / nn;
        float var = 0.f;
        for (int n = 0; n < NB; ++n) {
          int idx = b*NB + n;
          float d = l_sc[idx] - m;
          var += l_vl[idx]*d*d;
        }
        var /= nn;
        total += bgl + m + 0.5f*var;
      }
      out[(size_t)NI*IMH*IMW*3] = total;
    }
    return;
  }
  const int b = bid / (M*32);
  const int rem = bid - b*(M*32);
  const int j = rem >> 5, r = rem & 31;
  __shared__ int s_cp;
  __shared__ int s_pn[NB];
  __shared__ float s_ab[6];
  __shared__ unsigned s_mask[512];
  const unsigned* sch = ((const unsigned*)ws) + WS_SCH + b*32;
  if (tid == 0) s_cp = (int)sch[24 + L];
  __syncthreads();
  const int cp = s_cp;
  if (j >= cp) return;
  if (tid < cp) s_pn[tid] = (int)(((const unsigned*)ws) + WS_LIST + b*(MAXG*NB))[L*NB + tid];
  __syncthreads();
  float* __restrict__ img = out + (size_t)b*IMH*IMW*3;

  for (int jj = j; jj < cp; jj += M) {
    const int n = s_pn[jj];
    if (tid < 32) {
      const float* part = ws + WS_PART + (size_t)((b*NB + n)*32 + tid)*6;
      float v[6];
      #pragma unroll
      for (int k = 0; k < 6; ++k) v[k] = part[k];
      #pragma unroll
      for (int off = 16; off; off >>= 1)
        #pragma unroll
        for (int k = 0; k < 6; ++k) v[k] += __shfl_down(v[k], off, 32);
      if (tid == 0) {
        #pragma unroll
        for (int c = 0; c < 3; ++c) {
          float mu  = v[c]   * (1.0f/PP2);
          float var = v[3+c] * (1.0f/PP2) - mu*mu;
          float sd  = sqrtf(fmaxf(var, 0.f)) + 1e-6f;
          float alpha = sd / ws[3+c];
          s_ab[c]   = alpha;
          s_ab[3+c] = mu - ws[c]*alpha;
        }
      }
    }
    {
      const unsigned* mwords = ((const unsigned*)ws) + WS_MASK + (b*NB + n)*512;
      s_mask[tid]       = mwords[tid];
      s_mask[tid + 256] = mwords[tid + 256];
    }
    __syncthreads();
    const int* bi = (const int*)(ws + WS_BOX + (b*NB + n)*8);
    const int yi = bi[2], xi = bi[3], ph = bi[4];
    const float phf = (float)(ph > 1 ? ph : 1);
    const float* pbgp = ws + WS_PBG + (size_t)(b*NB + n)*PP2*3;
    const int tot = ph*ph;
    const int chunk = (tot + 31) / 32;
    const int i0 = r*chunk;
    const int i1 = min(tot, i0 + chunk);
    for (int idx = i0 + tid; idx < i1; idx += 256) {
      int rr = (int)((unsigned)idx / (unsigned)ph);
      int cx = idx - rr*ph;
      float v[3];
      analytic3(rr, cx, phf, pbgp, patch, s_mask, s_ab, v);
      float* dst = img + ((size_t)(yi + rr)*IMW + (xi + cx))*3;
      dst[0] = v[0]; dst[1] = v[1]; dst[2] = v[2];
    }
    __syncthreads();
  }
}

// ------ fb_k: serial per-image processing of lvl>=MAXG boxes (1024 threads) ------
__global__ __launch_bounds__(1024) void fb_k(
    float* __restrict__ out, const float* __restrict__ patch, float* __restrict__ ws)
{
  const int b = blockIdx.x, tid = threadIdx.x;
  const unsigned* sch = ((const unsigned*)ws) + WS_SCH + b*32;
  __shared__ float s_red[16][6];
  __shared__ float s_ab[6];
  __shared__ unsigned s_mask[512];
  float* __restrict__ img = out + (size_t)b*IMH*IMW*3;

  for (int n = 0; n < NB; ++n) {
    unsigned g = sch[n];
    if (g < (unsigned)MAXG || g == 255u) continue;
    const int* bi = (const int*)(ws + WS_BOX + (b*NB + n)*8);
    const int yi = bi[2], xi = bi[3], ph = bi[4];
    const float phf = (float)(ph > 1 ? ph : 1);
    float* __restrict__ pbg = ws + WS_PBG + (size_t)(b*NB + n)*PP2*3;

    float sm[3]={0,0,0}, sq[3]={0,0,0};
    #pragma unroll
    for (int k = 0; k < PP2/1024; ++k) {
      int idx = k*1024 + tid;
      int py = idx >> 7, px = idx & 127;
      float ys = ((float)yi + (py + 0.5f)*phf*(1.0f/PPX)) - 0.5f;
      float xs = ((float)xi + (px + 0.5f)*phf*(1.0f/PPX)) - 0.5f;
      ys = fminf(fmaxf(ys, 0.f), (float)(HP-1));
      xs = fminf(fmaxf(xs, 0.f), (float)(WP-1));
      float fy0 = floorf(ys), fx0 = floorf(xs);
      int y0 = (int)fy0, x0 = (int)fx0;
      int y1 = y0 + 1 < HP-1 ? y0 + 1 : HP-1;
      int x1 = x0 + 1 < WP-1 ? x0 + 1 : WP-1;
      float wy = ys - fy0, wx = xs - fx0;
      bool y0i = y0 < IMH, y1i = y1 < IMH, x0i = x0 < IMW, x1i = x1 < IMW;
      const float* r0 = img + (size_t)y0*IMW*3;
      const float* r1 = img + (size_t)y1*IMW*3;
      #pragma unroll
      for (int c = 0; c < 3; ++c) {
        float v00 = (y0i && x0i) ? r0[x0*3+c] : 0.f;
        float v01 = (y0i && x1i) ? r0[x1*3+c] : 0.f;
        float v10 = (y1i && x0i) ? r1[x0*3+c] : 0.f;
        float v11 = (y1i && x1i) ? r1[x1*3+c] : 0.f;
        float v = (1.f-wy)*((1.f-wx)*v00 + wx*v01) + wy*((1.f-wx)*v10 + wx*v11);
        pbg[idx*3+c] = v;
        sm[c] += v; sq[c] += v*v;
      }
    }
    float vals[6] = {sm[0],sm[1],sm[2],sq[0],sq[1],sq[2]};
    #pragma unroll
    for (int off = 32; off; off >>= 1)
      #pragma unroll
      for (int k = 0; k < 6; ++k) vals[k] += __shfl_down(vals[k], off);
    if ((tid & 63) == 0)
      for (int k = 0; k < 6; ++k) s_red[tid >> 6][k] = vals[k];
    if (tid < 512) {
      const unsigned* mwords = ((const unsigned*)ws) + WS_MASK + (b*NB + n)*512;
      s_mask[tid] = mwords[tid];
    }
    __syncthreads();
    if (tid == 0) {
      float acc[6] = {0,0,0,0,0,0};
      for (int w2 = 0; w2 < 16; ++w2)
        for (int k = 0; k < 6; ++k) acc[k] += s_red[w2][k];
      for (int c = 0; c < 3; ++c) {
        float mu  = acc[c]   * (1.0f/PP2);
        float var = acc[3+c] * (1.0f/PP2) - mu*mu;
        float sd  = sqrtf(fmaxf(var, 0.f)) + 1e-6f;
        float alpha = sd / ws[3+c];
        s_ab[c]   = alpha;
        s_ab[3+c] = mu - ws[c]*alpha;
      }
    }
    __syncthreads();
    const int tot = ph*ph;
    for (int idx = tid; idx < tot; idx += 1024) {
      int rr = (int)((unsigned)idx / (unsigned)ph);
      int cc = idx - rr*ph;
      float v[3];
      analytic3(rr, cc, phf, pbg, patch, s_mask, s_ab, v);
      float* dst = img + ((size_t)(yi + rr)*IMW + (xi + cc))*3;
      dst[0] = v[0]; dst[1] = v[1]; dst[2] = v[2];
    }
    __syncthreads();
  }
}

extern "C" void kernel_launch(void* const* d_in, const int* in_sizes, int n_in,
                              void* d_out, int out_size, void* d_ws, size_t ws_size,
                              hipStream_t stream) {
  const float* boxes  = (const float*)d_in[0];
  const float* images = (const float*)d_in[1];
  const float* patch  = (const float*)d_in[2];
  const float* Wsc    = (const float*)d_in[3];
  const float* bsc    = (const float*)d_in[4];
  const float* Wg     = (const float*)d_in[5];
  const float* bgv    = (const float*)d_in[6];
  float* out = (float*)d_out;
  float* ws  = (float*)d_ws;

  first_k<<<NCPY + NMB*8 + NCR0 + 2, 256, 0, stream>>>(
      out, images, boxes, Wsc, bsc, Wg, bgv, patch, ws);
  paste_k<<<NI*M1*32 + 1, 256, 0, stream>>>(out, patch, ws, 0, M1);  // + loss
  crop_k <<<NI*8*32, 256, 0, stream>>>(out, ws, 1, 8);
  paste_k<<<NI*8*32, 256, 0, stream>>>(out, patch, ws, 1, 8);
  crop_k <<<NI*4*32, 256, 0, stream>>>(out, ws, 2, 4);
  paste_k<<<NI*4*32, 256, 0, stream>>>(out, patch, ws, 2, 4);
  crop_k <<<NI*2*32, 256, 0, stream>>>(out, ws, 3, 2);
  paste_k<<<NI*2*32, 256, 0, stream>>>(out, patch, ws, 3, 2);
  crop_k <<<NI*2*32, 256, 0, stream>>>(out, ws, 4, 2);
  paste_k<<<NI*2*32, 256, 0, stream>>>(out, patch, ws, 4, 2);
  crop_k <<<NI*2*32, 256, 0, stream>>>(out, ws, 5, 2);
  paste_k<<<NI*2*32, 256, 0, stream>>>(out, patch, ws, 5, 2);
  fb_k<<<NI, 1024, 0, stream>>>(out, patch, ws);
}

// Round 19
// 176.903 us; speedup vs baseline: 1.0246x; 1.0246x over previous
//
#include <hip/hip_runtime.h>

#define PPX  128
#define PP2  16384
#define IMH  896
#define IMW  896
#define NB   24
#define NI   8
#define HP   1152
#define WP   1152
#define MAXG 6              // scheduled levels 0..5; lvl>=6 -> fallback (rare)
#define NMB8 (NI*NB*8)      // 1536 mask blocks
#define NCPY 2048
#define NCR0 (NI*NB*16)     // 3072 crop0 blocks (16 per box, 2 sub-blocks each)
#define M1   12

// ws layout (float units):
// [0..5]                      mu_p[3], sd_p[3]
// [8 .. 8+192*8)              per-box structs
// [2048 .. +192*512)          mask bitmaps (uint32)
// [100352 .. +8*32)           schedule: per image lvl[24] + cnt[MAXG] at [24..] (uint32)
// [100608 .. +8*6*24)         member lists [img][lvl][24] (uint32)
// [101760 .. +192*8)          mask-sum partials [box][chunk]
// [103424 .. +8*24*32*6)      partial stats [box][blk][6]
// [140288 .. +8*24*PP2*3)     pbg slot per box (~38 MB)
#define WS_BOX  8
#define WS_MASK 2048
#define WS_SCH  100352
#define WS_LIST 100608
#define WS_MSUM 101760
#define WS_PART 103424
#define WS_PBG  140288

__device__ __forceinline__ void box_geom(const float* __restrict__ bx,
    const float* __restrict__ Wsc, const float* __restrict__ bsc,
    float& scale, float& ps, int& yi, int& xi, int& ph, int& vld)
{
  float ya=bx[0], xa=bx[1], yb=bx[2], xb=bx[3];
  float bh=(yb-ya)/(float)IMH, bw=(xb-xa)/(float)IMW;
  float z = bh*Wsc[0]+bw*Wsc[1]+bsc[0];
  float sig = 1.f/(1.f+expf(-z));
  scale = sig*0.4f;
  float h=yb-ya, w=xb-xa;
  ps = floorf(sqrtf((h*w)*scale));
  float oy=ya+h*0.5f, ox=xa+w*0.5f;
  float ymp=fmaxf(oy-ps*0.5f,0.f), xmp=fmaxf(ox-ps*0.5f,0.f);
  if (ymp+ps>(float)IMH) ymp=(float)IMH-ps;
  if (xmp+ps>(float)IMW) xmp=(float)IMW-ps;
  yi=(int)ymp; xi=(int)xmp; ph=(int)ps;
  vld = (ps>60.f) ? 1 : 0;
}

// paste value at region-relative (rr,cc); expressions verbatim from passing rounds.
__device__ __forceinline__ void analytic3(int rr, int cc, float phf,
    const float* __restrict__ pbg1, const float* __restrict__ patch,
    const unsigned* msk, const float* ab, float v[3])
{
  float sy = ((rr + 0.5f)*128.0f)/phf - 0.5f;
  float sx = ((cc + 0.5f)*128.0f)/phf - 0.5f;
  sy = fminf(fmaxf(sy, 0.f), 127.f);
  sx = fminf(fmaxf(sx, 0.f), 127.f);
  float fy0 = floorf(sy), fx0 = floorf(sx);
  int py0 = (int)fy0, px0 = (int)fx0;
  int py1 = py0 + 1 < 127 ? py0 + 1 : 127;
  int px1 = px0 + 1 < 127 ? px0 + 1 : 127;
  float wy = sy - fy0, wx = sx - fx0;
  int i00 = (py0<<7)+px0, i01 = (py0<<7)+px1, i10 = (py1<<7)+px0, i11 = (py1<<7)+px1;
  bool m00 = (msk[i00>>5] >> (i00&31)) & 1u;
  bool m01 = (msk[i01>>5] >> (i01&31)) & 1u;
  bool m10 = (msk[i10>>5] >> (i10&31)) & 1u;
  bool m11 = (msk[i11>>5] >> (i11&31)) & 1u;
  #pragma unroll
  for (int ch = 0; ch < 3; ++ch) {
    float a = ab[ch], be = ab[3+ch];
    float t00 = m00 ? patch[i00*3+ch]*a + be : pbg1[i00*3+ch];
    float t01 = m01 ? patch[i01*3+ch]*a + be : pbg1[i01*3+ch];
    float t10 = m10 ? patch[i10*3+ch]*a + be : pbg1[i10*3+ch];
    float t11 = m11 ? patch[i11*3+ch]*a + be : pbg1[i11*3+ch];
    v[ch] = (1.f-wy)*((1.f-wx)*t00 + wx*t01) + wy*((1.f-wx)*t10 + wx*t11);
  }
}

// plain crop with explicit geom: box n of image b, block blk (512 px), from src.
__device__ __forceinline__ void crop_geom(
    const float* __restrict__ src, float* __restrict__ ws, int b, int n,
    int yi, int xi, int ph, int blk, float (*s_red)[6])
{
  const int tid = threadIdx.x;
  const float phf = (float)(ph > 1 ? ph : 1);
  float* __restrict__ pbg = ws + WS_PBG + (size_t)(b*NB + n)*PP2*3;
  float sm[3] = {0,0,0}, sq[3] = {0,0,0};
  #pragma unroll
  for (int k = 0; k < 2; ++k) {
    int idx = blk*512 + k*256 + tid;
    int py = idx >> 7, px = idx & 127;
    float ys = ((float)yi + (py + 0.5f)*phf*(1.0f/PPX)) - 0.5f;
    float xs = ((float)xi + (px + 0.5f)*phf*(1.0f/PPX)) - 0.5f;
    ys = fminf(fmaxf(ys, 0.f), (float)(HP-1));
    xs = fminf(fmaxf(xs, 0.f), (float)(WP-1));
    float fy0 = floorf(ys), fx0 = floorf(xs);
    int y0 = (int)fy0, x0 = (int)fx0;
    int y1 = y0 + 1 < HP-1 ? y0 + 1 : HP-1;
    int x1 = x0 + 1 < WP-1 ? x0 + 1 : WP-1;
    float wy = ys - fy0, wx = xs - fx0;
    bool y0i = y0 < IMH, y1i = y1 < IMH, x0i = x0 < IMW, x1i = x1 < IMW;
    const float* r0 = src + (size_t)y0*IMW*3;
    const float* r1 = src + (size_t)y1*IMW*3;
    #pragma unroll
    for (int c = 0; c < 3; ++c) {
      float v00 = (y0i && x0i) ? r0[x0*3+c] : 0.f;
      float v01 = (y0i && x1i) ? r0[x1*3+c] : 0.f;
      float v10 = (y1i && x0i) ? r1[x0*3+c] : 0.f;
      float v11 = (y1i && x1i) ? r1[x1*3+c] : 0.f;
      float v = (1.f-wy)*((1.f-wx)*v00 + wx*v01) + wy*((1.f-wx)*v10 + wx*v11);
      pbg[idx*3+c] = v;
      sm[c] += v; sq[c] += v*v;
    }
  }
  float vals[6] = {sm[0],sm[1],sm[2],sq[0],sq[1],sq[2]};
  #pragma unroll
  for (int off = 32; off; off >>= 1)
    #pragma unroll
    for (int k = 0; k < 6; ++k) vals[k] += __shfl_down(vals[k], off);
  int wid = tid >> 6;
  __syncthreads();
  if ((tid & 63) == 0)
    for (int k = 0; k < 6; ++k) s_red[wid][k] = vals[k];
  __syncthreads();
  if (tid == 0) {
    float* part = ws + WS_PART + (size_t)((b*NB + n)*32 + blk)*6;
    for (int k = 0; k < 6; ++k)
      part[k] = s_red[0][k] + s_red[1][k] + s_red[2][k] + s_red[3][k];
  }
  __syncthreads();
}

// --- first_k: [copy 2048 FRONT | masks 1536 | crop0 3072 | stats | sched] ---
__global__ __launch_bounds__(256) void first_k(
    float* __restrict__ out, const float* __restrict__ images,
    const float* __restrict__ boxes,
    const float* __restrict__ Wsc, const float* __restrict__ bsc,
    const float* __restrict__ Wg, const float* __restrict__ bgv,
    const float* __restrict__ patch, float* __restrict__ ws)
{
  const int bid = blockIdx.x, tid = threadIdx.x;

  if (bid < NCPY) {
    // ---- dedicated copy blocks at the FRONT: start at t=0, full width ----
    const float4* src4 = (const float4*)images;
    float4* dst4 = (float4*)out;
    const int n4 = NI*IMH*IMW*3/4;
    for (int i = bid*256 + tid; i < n4; i += NCPY*256) dst4[i] = src4[i];
    return;
  }

  if (bid < NCPY + NMB8) {
    // ---- mask chunk q of box bn ----
    const int w = bid - NCPY;
    const int bn = w >> 3, q = w & 7;
    float bh = (boxes[bn*4+2]-boxes[bn*4+0])/(float)IMH;
    float bw = (boxes[bn*4+3]-boxes[bn*4+1])/(float)IMW;
    unsigned* mwords = ((unsigned*)ws) + WS_MASK + bn*512;
    float lsum = 0.f;
    const int lane = tid & 63;
    #pragma unroll
    for (int i = 0; i < 8; ++i) {
      int p = q*2048 + i*256 + tid;
      float zz = bh*Wg[p] + bw*Wg[PP2 + p] + bgv[p];
      lsum += 1.0f / (1.0f + expf(-zz));
      unsigned long long m = __ballot(zz > 0.0f);
      if (lane == 0) {
        int base = p >> 5;
        mwords[base]   = (unsigned)(m & 0xffffffffULL);
        mwords[base+1] = (unsigned)(m >> 32);
      }
    }
    #pragma unroll
    for (int off = 32; off; off >>= 1) lsum += __shfl_down(lsum, off);
    __shared__ float s_r[4];
    if ((tid & 63) == 0) s_r[tid >> 6] = lsum;
    __syncthreads();
    if (tid == 0) ws[WS_MSUM + bn*8 + q] = s_r[0] + s_r[1] + s_r[2] + s_r[3];
    return;
  }

  if (bid < NCPY + NMB8 + NCR0) {
    // ---- crop0: box n of image b, 16 blocks/box, 2 sub-blocks each.
    //      membership (level 0) self-determined: valid & no earlier valid overlap.
    const int w = bid - NCPY - NMB8;
    const int b = w / (NB*16);
    const int rem = w - b*(NB*16);
    const int n = rem >> 4, blk16 = rem & 15;
    __shared__ int s_yi[NB], s_xi[NB], s_ph[NB], s_vl[NB];
    __shared__ int s_ok;
    __shared__ float s_red[4][6];
    if (tid < NB) {
      float scale, ps; int yi, xi, ph, vld;
      box_geom(boxes + (b*NB + tid)*4, Wsc, bsc, scale, ps, yi, xi, ph, vld);
      s_yi[tid]=yi; s_xi[tid]=xi; s_ph[tid]=ph; s_vl[tid]=vld;
    }
    __syncthreads();
    if (tid == 0) {
      int ok = s_vl[n];
      if (ok) {
        int y0=s_yi[n]-2, y1=s_yi[n]+s_ph[n]+3;
        int x0=s_xi[n]-2, x1=s_xi[n]+s_ph[n]+3;
        for (int m = 0; m < n; ++m) {
          if (!s_vl[m]) continue;
          int my0=s_yi[m]-2, my1=s_yi[m]+s_ph[m]+3;
          int mx0=s_xi[m]-2, mx1=s_xi[m]+s_ph[m]+3;
          if (y0<my1 && my0<y1 && x0<mx1 && mx0<x1) { ok = 0; break; }
        }
      }
      s_ok = ok;
    }
    __syncthreads();
    if (!s_ok) return;
    const float* src = images + (size_t)b*IMH*IMW*3;
    crop_geom(src, ws, b, n, s_yi[n], s_xi[n], s_ph[n], blk16*2,     s_red);
    crop_geom(src, ws, b, n, s_yi[n], s_xi[n], s_ph[n], blk16*2 + 1, s_red);
    return;
  }

  if (bid == NCPY + NMB8 + NCR0) {
    // ---- patch stats ----
    __shared__ float s_red6[256][6];
    float s0=0,s1=0,s2=0,q0=0,q1=0,q2=0;
    for (int i = tid; i < PP2; i += 256) {
      float a = patch[i*3+0], b = patch[i*3+1], c = patch[i*3+2];
      s0+=a; s1+=b; s2+=c; q0+=a*a; q1+=b*b; q2+=c*c;
    }
    s_red6[tid][0]=s0; s_red6[tid][1]=s1; s_red6[tid][2]=s2;
    s_red6[tid][3]=q0; s_red6[tid][4]=q1; s_red6[tid][5]=q2;
    __syncthreads();
    for (int s = 128; s > 0; s >>= 1) {
      if (tid < s)
        for (int k=0;k<6;++k) s_red6[tid][k] += s_red6[tid+s][k];
      __syncthreads();
    }
    if (tid == 0) {
      for (int c=0;c<3;++c) {
        float mu  = s_red6[0][c]   * (1.0f/PP2);
        float var = s_red6[0][3+c] * (1.0f/PP2) - mu*mu;
        float sd  = sqrtf(fmaxf(var, 0.f)) + 1e-6f;
        ws[c] = mu; ws[3+c] = sd;
      }
    }
    return;
  }

  // ---- last block: structs + per-image level schedule + member lists ----
  {
    __shared__ int g_yi[NI*NB], g_xi[NI*NB], g_ph[NI*NB], g_vl[NI*NB];
    if (tid < NI*NB) {
      float scale, ps; int yi, xi, ph, vld;
      box_geom(boxes + tid*4, Wsc, bsc, scale, ps, yi, xi, ph, vld);
      g_yi[tid]=yi; g_xi[tid]=xi; g_ph[tid]=ph; g_vl[tid]=vld;
      float* bst = ws + WS_BOX + tid*8;
      bst[0] = scale;
      bst[1] = ps;
      ((int*)bst)[2] = yi;
      ((int*)bst)[3] = xi;
      ((int*)bst)[4] = ph;
      bst[5] = vld ? 1.f : 0.f;
    }
    __syncthreads();
    if (tid < NI) {
      unsigned* sch = ((unsigned*)ws) + WS_SCH + tid*32;
      unsigned* lst = ((unsigned*)ws) + WS_LIST + tid*(MAXG*NB);
      int lv[NB];
      int cnt[MAXG];
      for (int L = 0; L < MAXG; ++L) cnt[L] = 0;
      for (int n = 0; n < NB; ++n) {
        int idx = tid*NB + n;
        if (!g_vl[idx]) { lv[n] = -1; sch[n] = 255u; continue; }
        int y0 = g_yi[idx]-2, y1 = g_yi[idx]+g_ph[idx]+3;
        int x0 = g_xi[idx]-2, x1 = g_xi[idx]+g_ph[idx]+3;
        int L = 0;
        for (int m = 0; m < n; ++m) {
          if (lv[m] < 0) continue;
          int mi = tid*NB + m;
          int my0 = g_yi[mi]-2, my1 = g_yi[mi]+g_ph[mi]+3;
          int mx0 = g_xi[mi]-2, mx1 = g_xi[mi]+g_ph[mi]+3;
          if (y0 < my1 && my0 < y1 && x0 < mx1 && mx0 < x1)
            L = max(L, lv[m] + 1);
        }
        lv[n] = L;
        sch[n] = (unsigned)L;
        if (L < MAXG) lst[L*NB + cnt[L]++] = (unsigned)n;
      }
      for (int L = 0; L < MAXG; ++L) sch[24 + L] = (unsigned)cnt[L];
    }
  }
}

// ------ crop_k: crop level L (>=1) from out ------
__global__ __launch_bounds__(256) void crop_k(
    float* __restrict__ out, float* __restrict__ ws, int L, int M)
{
  const int bid = blockIdx.x, tid = threadIdx.x;
  const int b = bid / (M*32);
  const int rem = bid - b*(M*32);
  const int j = rem >> 5, blk = rem & 31;
  __shared__ float s_red[4][6];
  __shared__ int s_cn[NB];
  __shared__ int s_cc;
  const unsigned* sch = ((const unsigned*)ws) + WS_SCH + b*32;
  if (tid == 0) s_cc = (int)sch[24 + L];
  __syncthreads();
  const int cc = s_cc;
  if (j >= cc) return;
  if (tid < cc) s_cn[tid] = (int)(((const unsigned*)ws) + WS_LIST + b*(MAXG*NB))[L*NB + tid];
  __syncthreads();
  const float* src = out + (size_t)b*IMH*IMW*3;
  for (int jj = j; jj < cc; jj += M) {
    const int n = s_cn[jj];
    const int* bi = (const int*)(ws + WS_BOX + (b*NB + n)*8);
    crop_geom(src, ws, b, n, bi[2], bi[3], bi[4], blk, s_red);
  }
}

// ------ paste_k: paste level L; P0 grid has +1 loss block ------
__global__ __launch_bounds__(256) void paste_k(
    float* __restrict__ out, const float* __restrict__ patch,
    float* __restrict__ ws, int L, int M)
{
  const int bid = blockIdx.x, tid = threadIdx.x;
  if (bid >= NI*M*32) {
    // loss block (only in P0's grid)
    __shared__ float l_sc[NI*NB], l_ms[NI*NB], l_vl[NI*NB];
    if (tid < NI*NB) {
      const float* bst = ws + WS_BOX + tid*8;
      l_sc[tid] = bst[0]; l_vl[tid] = bst[5];
      float ms = 0.f;
      for (int q = 0; q < 8; ++q) ms += ws[WS_MSUM + tid*8 + q];
      l_ms[tid] = ms;
    }
    __syncthreads();
    if (tid == 0) {
      float total = 0.f;
      for (int b = 0; b < NI; ++b) {
        float sum_s = 0.f, cnt = 0.f, bgl = 0.f;
        for (int n = 0; n < NB; ++n) {
          int idx = b*NB + n;
          float v = l_vl[idx];
          sum_s += l_sc[idx]*v; cnt += v; bgl += (l_ms[idx]*(1.0f/PP2))*v;
        }
        float nn = fmaxf(cnt, 1.0f);
        float m = sum_s / nn;
        float var = 0.f;
        for (int n = 0; n < NB; ++n) {
          int idx = b*NB + n;
          float d = l_sc[idx] - m;
          var += l_vl[idx]*d*d;
        }
        var /= nn;
        total += bgl + m + 0.5f*var;
      }
      out[(size_t)NI*IMH*IMW*3] = total;
    }
    return;
  }
  const int b = bid / (M*32);
  const int rem = bid - b*(M*32);
  const int j = rem >> 5, r = rem & 31;
  __shared__ int s_cp;
  __shared__ int s_pn[NB];
  __shared__ float s_ab[6];
  __shared__ unsigned s_mask[512];
  const unsigned* sch = ((const unsigned*)ws) + WS_SCH + b*32;
  if (tid == 0) s_cp = (int)sch[24 + L];
  __syncthreads();
  const int cp = s_cp;
  if (j >= cp) return;
  if (tid < cp) s_pn[tid] = (int)(((const unsigned*)ws) + WS_LIST + b*(MAXG*NB))[L*NB + tid];
  __syncthreads();
  float* __restrict__ img = out + (size_t)b*IMH*IMW*3;

  for (int jj = j; jj < cp; jj += M) {
    const int n = s_pn[jj];
    if (tid < 32) {
      const float* part = ws + WS_PART + (size_t)((b*NB + n)*32 + tid)*6;
      float v[6];
      #pragma unroll
      for (int k = 0; k < 6; ++k) v[k] = part[k];
      #pragma unroll
      for (int off = 16; off; off >>= 1)
        #pragma unroll
        for (int k = 0; k < 6; ++k) v[k] += __shfl_down(v[k], off, 32);
      if (tid == 0) {
        #pragma unroll
        for (int c = 0; c < 3; ++c) {
          float mu  = v[c]   * (1.0f/PP2);
          float var = v[3+c] * (1.0f/PP2) - mu*mu;
          float sd  = sqrtf(fmaxf(var, 0.f)) + 1e-6f;
          float alpha = sd / ws[3+c];
          s_ab[c]   = alpha;
          s_ab[3+c] = mu - ws[c]*alpha;
        }
      }
    }
    {
      const unsigned* mwords = ((const unsigned*)ws) + WS_MASK + (b*NB + n)*512;
      s_mask[tid]       = mwords[tid];
      s_mask[tid + 256] = mwords[tid + 256];
    }
    __syncthreads();
    const int* bi = (const int*)(ws + WS_BOX + (b*NB + n)*8);
    const int yi = bi[2], xi = bi[3], ph = bi[4];
    const float phf = (float)(ph > 1 ? ph : 1);
    const float* pbgp = ws + WS_PBG + (size_t)(b*NB + n)*PP2*3;
    const int tot = ph*ph;
    const int chunk = (tot + 31) / 32;
    const int i0 = r*chunk;
    const int i1 = min(tot, i0 + chunk);
    for (int idx = i0 + tid; idx < i1; idx += 256) {
      int rr = (int)((unsigned)idx / (unsigned)ph);
      int cx = idx - rr*ph;
      float v[3];
      analytic3(rr, cx, phf, pbgp, patch, s_mask, s_ab, v);
      float* dst = img + ((size_t)(yi + rr)*IMW + (xi + cx))*3;
      dst[0] = v[0]; dst[1] = v[1]; dst[2] = v[2];
    }
    __syncthreads();
  }
}

// ------ fb_k: serial per-image processing of lvl>=MAXG boxes (1024 threads) ------
__global__ __launch_bounds__(1024) void fb_k(
    float* __restrict__ out, const float* __restrict__ patch, float* __restrict__ ws)
{
  const int b = blockIdx.x, tid = threadIdx.x;
  const unsigned* sch = ((const unsigned*)ws) + WS_SCH + b*32;
  __shared__ float s_red[16][6];
  __shared__ float s_ab[6];
  __shared__ unsigned s_mask[512];
  float* __restrict__ img = out + (size_t)b*IMH*IMW*3;

  for (int n = 0; n < NB; ++n) {
    unsigned g = sch[n];
    if (g < (unsigned)MAXG || g == 255u) continue;
    const int* bi = (const int*)(ws + WS_BOX + (b*NB + n)*8);
    const int yi = bi[2], xi = bi[3], ph = bi[4];
    const float phf = (float)(ph > 1 ? ph : 1);
    float* __restrict__ pbg = ws + WS_PBG + (size_t)(b*NB + n)*PP2*3;

    float sm[3]={0,0,0}, sq[3]={0,0,0};
    #pragma unroll
    for (int k = 0; k < PP2/1024; ++k) {
      int idx = k*1024 + tid;
      int py = idx >> 7, px = idx & 127;
      float ys = ((float)yi + (py + 0.5f)*phf*(1.0f/PPX)) - 0.5f;
      float xs = ((float)xi + (px + 0.5f)*phf*(1.0f/PPX)) - 0.5f;
      ys = fminf(fmaxf(ys, 0.f), (float)(HP-1));
      xs = fminf(fmaxf(xs, 0.f), (float)(WP-1));
      float fy0 = floorf(ys), fx0 = floorf(xs);
      int y0 = (int)fy0, x0 = (int)fx0;
      int y1 = y0 + 1 < HP-1 ? y0 + 1 : HP-1;
      int x1 = x0 + 1 < WP-1 ? x0 + 1 : WP-1;
      float wy = ys - fy0, wx = xs - fx0;
      bool y0i = y0 < IMH, y1i = y1 < IMH, x0i = x0 < IMW, x1i = x1 < IMW;
      const float* r0 = img + (size_t)y0*IMW*3;
      const float* r1 = img + (size_t)y1*IMW*3;
      #pragma unroll
      for (int c = 0; c < 3; ++c) {
        float v00 = (y0i && x0i) ? r0[x0*3+c] : 0.f;
        float v01 = (y0i && x1i) ? r0[x1*3+c] : 0.f;
        float v10 = (y1i && x0i) ? r1[x0*3+c] : 0.f;
        float v11 = (y1i && x1i) ? r1[x1*3+c] : 0.f;
        float v = (1.f-wy)*((1.f-wx)*v00 + wx*v01) + wy*((1.f-wx)*v10 + wx*v11);
        pbg[idx*3+c] = v;
        sm[c] += v; sq[c] += v*v;
      }
    }
    float vals[6] = {sm[0],sm[1],sm[2],sq[0],sq[1],sq[2]};
    #pragma unroll
    for (int off = 32; off; off >>= 1)
      #pragma unroll
      for (int k = 0; k < 6; ++k) vals[k] += __shfl_down(vals[k], off);
    if ((tid & 63) == 0)
      for (int k = 0; k < 6; ++k) s_red[tid >> 6][k] = vals[k];
    if (tid < 512) {
      const unsigned* mwords = ((const unsigned*)ws) + WS_MASK + (b*NB + n)*512;
      s_mask[tid] = mwords[tid];
    }
    __syncthreads();
    if (tid == 0) {
      float acc[6] = {0,0,0,0,0,0};
      for (int w2 = 0; w2 < 16; ++w2)
        for (int k = 0; k < 6; ++k) acc[k] += s_red[w2][k];
      for (int c = 0; c < 3; ++c) {
        float mu  = acc[c]   * (1.0f/PP2);
        float var = acc[3+c] * (1.0f/PP2) - mu*mu;
        float sd  = sqrtf(fmaxf(var, 0.f)) + 1e-6f;
        float alpha = sd / ws[3+c];
        s_ab[c]   = alpha;
        s_ab[3+c] = mu - ws[c]*alpha;
      }
    }
    __syncthreads();
    const int tot = ph*ph;
    for (int idx = tid; idx < tot; idx += 1024) {
      int rr = (int)((unsigned)idx / (unsigned)ph);
      int cc = idx - rr*ph;
      float v[3];
      analytic3(rr, cc, phf, pbg, patch, s_mask, s_ab, v);
      float* dst = img + ((size_t)(yi + rr)*IMW + (xi + cc))*3;
      dst[0] = v[0]; dst[1] = v[1]; dst[2] = v[2];
    }
    __syncthreads();
  }
}

extern "C" void kernel_launch(void* const* d_in, const int* in_sizes, int n_in,
                              void* d_out, int out_size, void* d_ws, size_t ws_size,
                              hipStream_t stream) {
  const float* boxes  = (const float*)d_in[0];
  const float* images = (const float*)d_in[1];
  const float* patch  = (const float*)d_in[2];
  const float* Wsc    = (const float*)d_in[3];
  const float* bsc    = (const float*)d_in[4];
  const float* Wg     = (const float*)d_in[5];
  const float* bgv    = (const float*)d_in[6];
  float* out = (float*)d_out;
  float* ws  = (float*)d_ws;

  first_k<<<NCPY + NMB8 + NCR0 + 2, 256, 0, stream>>>(
      out, images, boxes, Wsc, bsc, Wg, bgv, patch, ws);
  paste_k<<<NI*M1*32 + 1, 256, 0, stream>>>(out, patch, ws, 0, M1);  // + loss
  crop_k <<<NI*8*32, 256, 0, stream>>>(out, ws, 1, 8);
  paste_k<<<NI*8*32, 256, 0, stream>>>(out, patch, ws, 1, 8);
  crop_k <<<NI*4*32, 256, 0, stream>>>(out, ws, 2, 4);
  paste_k<<<NI*4*32, 256, 0, stream>>>(out, patch, ws, 2, 4);
  crop_k <<<NI*2*32, 256, 0, stream>>>(out, ws, 3, 2);
  paste_k<<<NI*2*32, 256, 0, stream>>>(out, patch, ws, 3, 2);
  crop_k <<<NI*2*32, 256, 0, stream>>>(out, ws, 4, 2);
  paste_k<<<NI*2*32, 256, 0, stream>>>(out, patch, ws, 4, 2);
  crop_k <<<NI*2*32, 256, 0, stream>>>(out, ws, 5, 2);
  paste_k<<<NI*2*32, 256, 0, stream>>>(out, patch, ws, 5, 2);
  fb_k<<<NI, 1024, 0, stream>>>(out, patch, ws);
}